// Round 1
// baseline (40.298 us; speedup 1.0000x reference)
//
#include <hip/hip_runtime.h>

// Gaussian3D: values (M,F=1) + weights (M,N) from 3D gaussian influence.
// M=8192 points, N=4096 gaussians, F=1.
// d_out layout: [values (M*F) | weights (M*N)], float32.

#define THREADS 256
#define N_PER_THREAD 4
#define N_PER_BLOCK (THREADS * N_PER_THREAD)  // 1024
#define M_PER_BLOCK 16

// ---------------- kernel 1: per-gaussian precompute ----------------
// packs per gaussian n: P[3n+0]={x,y,z,opacity} P[3n+1]={i00,i01,i02,i11}
//                       P[3n+2]={i12,i22,feat,0}
__global__ void gauss_precomp(const float* __restrict__ xyz,
                              const float* __restrict__ scale_raw,
                              const float* __restrict__ rot_raw,
                              const float* __restrict__ op_raw,
                              const float* __restrict__ feat,
                              float4* __restrict__ P, int N) {
  int n = blockIdx.x * blockDim.x + threadIdx.x;
  if (n >= N) return;
  float qw = rot_raw[4*n+0], qx = rot_raw[4*n+1], qy = rot_raw[4*n+2], qz = rot_raw[4*n+3];
  float inorm = rsqrtf(qw*qw + qx*qx + qy*qy + qz*qz);
  qw *= inorm; qx *= inorm; qy *= inorm; qz *= inorm;
  float sx = expf(scale_raw[3*n+0]);
  float sy = expf(scale_raw[3*n+1]);
  float sz = expf(scale_raw[3*n+2]);
  float r00 = 1.f - 2.f*(qy*qy + qz*qz);
  float r01 = 2.f*(qx*qy - qw*qz);
  float r02 = 2.f*(qx*qz + qw*qy);
  float r10 = 2.f*(qx*qy + qw*qz);
  float r11 = 1.f - 2.f*(qx*qx + qz*qz);
  float r12 = 2.f*(qy*qz - qw*qx);
  float r20 = 2.f*(qx*qz - qw*qy);
  float r21 = 2.f*(qy*qz + qw*qx);
  float r22 = 1.f - 2.f*(qx*qx + qy*qy);
  // RS[i][k] = R[i][k]*s[k]; cov = RS * RS^T (symmetric, 6 uniques)
  float a0 = r00*sx, a1 = r01*sy, a2 = r02*sz;
  float b0 = r10*sx, b1 = r11*sy, b2 = r12*sz;
  float c0 = r20*sx, c1 = r21*sy, c2 = r22*sz;
  float c00 = a0*a0 + a1*a1 + a2*a2;
  float c01 = a0*b0 + a1*b1 + a2*b2;
  float c02 = a0*c0 + a1*c1 + a2*c2;
  float c11 = b0*b0 + b1*b1 + b2*b2;
  float c12 = b0*c0 + b1*c1 + b2*c2;
  float c22 = c0*c0 + c1*c1 + c2*c2;
  // symmetric 3x3 inverse via adjugate
  float m00 = c11*c22 - c12*c12;
  float m01 = c02*c12 - c01*c22;
  float m02 = c01*c12 - c02*c11;
  float det = c00*m00 + c01*m01 + c02*m02;
  float idet = 1.f / det;
  float i00 = m00*idet;
  float i01 = m01*idet;
  float i02 = m02*idet;
  float i11 = (c00*c22 - c02*c02)*idet;
  float i12 = (c02*c01 - c00*c12)*idet;
  float i22 = (c00*c11 - c01*c01)*idet;
  float op = 1.f / (1.f + expf(-op_raw[n]));
  float f  = feat[n];
  P[n*3+0] = make_float4(xyz[3*n+0], xyz[3*n+1], xyz[3*n+2], op);
  P[n*3+1] = make_float4(i00, i01, i02, i11);
  P[n*3+2] = make_float4(i12, i22, f, 0.f);
}

// ---------------- kernel 2: M x N sweep ----------------
// block: 256 threads, each thread owns 4 consecutive n (params in regs),
// loops over M_PER_BLOCK rows. weights written as float4 per thread per row.
// per-row value partial: wave shfl reduce -> partials[m*16 + p].
__global__ __launch_bounds__(THREADS) void gauss_sweep(
    const float* __restrict__ points,
    const float4* __restrict__ P,
    float* __restrict__ weights,      // d_out + M*F
    float* __restrict__ partials,     // [M][16]
    int M, int N) {
  const int t = threadIdx.x;
  const int n0 = blockIdx.x * N_PER_BLOCK + t * N_PER_THREAD;
  const int mbase = blockIdx.y * M_PER_BLOCK;

  // load 4 gaussians into registers
  float4 ga[N_PER_THREAD], gb[N_PER_THREAD], gc[N_PER_THREAD];
#pragma unroll
  for (int j = 0; j < N_PER_THREAD; ++j) {
    int n = n0 + j;
    ga[j] = P[n*3+0];  // x,y,z,op
    gb[j] = P[n*3+1];  // i00,i01,i02,i11
    gc[j] = P[n*3+2];  // i12,i22,f,pad
  }

  const int wave = t >> 6;                       // 0..3
  const int pidx = blockIdx.x * 4 + wave;        // 0..15 partial slot

#pragma unroll 4
  for (int i = 0; i < M_PER_BLOCK; ++i) {
    const int m = mbase + i;                     // block-uniform -> scalar loads
    const float px = points[3*m+0];
    const float py = points[3*m+1];
    const float pz = points[3*m+2];

    float4 w;
    float vsum = 0.f;
#pragma unroll
    for (int j = 0; j < N_PER_THREAD; ++j) {
      const float dx = px - ga[j].x;
      const float dy = py - ga[j].y;
      const float dz = pz - ga[j].z;
      const float t0 = gb[j].x*dx + gb[j].y*dy + gb[j].z*dz;
      const float t1 = gb[j].y*dx + gb[j].w*dy + gc[j].x*dz;
      const float t2 = gb[j].z*dx + gc[j].x*dy + gc[j].y*dz;
      const float mahal = dx*t0 + dy*t1 + dz*t2;
      const float wj = __expf(-0.5f * mahal) * ga[j].w;
      (&w.x)[j] = wj;
      vsum += wj * gc[j].z;
    }
    *(float4*)&weights[(size_t)m * N + n0] = w;

    // wave-level reduce (64 lanes)
#pragma unroll
    for (int off = 32; off >= 1; off >>= 1)
      vsum += __shfl_xor(vsum, off, 64);
    if ((t & 63) == 0)
      partials[(size_t)m * 16 + pidx] = vsum;
  }
}

// ---------------- kernel 3: finalize values ----------------
__global__ void gauss_finalize(const float* __restrict__ partials,
                               float* __restrict__ values, int M) {
  int m = blockIdx.x * blockDim.x + threadIdx.x;
  if (m >= M) return;
  const float4* p = (const float4*)&partials[(size_t)m * 16];
  float4 a = p[0], b = p[1], c = p[2], d = p[3];
  values[m] = ((a.x + a.y) + (a.z + a.w)) + ((b.x + b.y) + (b.z + b.w)) +
              ((c.x + c.y) + (c.z + c.w)) + ((d.x + d.y) + (d.z + d.w));
}

extern "C" void kernel_launch(void* const* d_in, const int* in_sizes, int n_in,
                              void* d_out, int out_size, void* d_ws, size_t ws_size,
                              hipStream_t stream) {
  const float* points   = (const float*)d_in[0];
  const float* xyz      = (const float*)d_in[1];
  const float* scale_raw= (const float*)d_in[2];
  const float* rot_raw  = (const float*)d_in[3];
  const float* op_raw   = (const float*)d_in[4];
  const float* feat     = (const float*)d_in[5];

  const int M = in_sizes[0] / 3;   // 8192
  const int N = in_sizes[1] / 3;   // 4096
  const int F = in_sizes[5] / N;   // 1 (kernel assumes F==1)
  (void)F;

  float* values  = (float*)d_out;              // M*F floats
  float* weights = (float*)d_out + (size_t)M;  // M*N floats

  float4* P       = (float4*)d_ws;                         // N*3 float4 = 192KB
  float* partials = (float*)((char*)d_ws + (size_t)N * 48); // M*16 floats = 512KB

  gauss_precomp<<<(N + THREADS - 1) / THREADS, THREADS, 0, stream>>>(
      xyz, scale_raw, rot_raw, op_raw, feat, P, N);

  dim3 grid(N / N_PER_BLOCK, M / M_PER_BLOCK);  // (4, 512)
  gauss_sweep<<<grid, THREADS, 0, stream>>>(points, P, weights, partials, M, N);

  gauss_finalize<<<(M + THREADS - 1) / THREADS, THREADS, 0, stream>>>(
      partials, values, M);
}

// Round 2
// 38.740 us; speedup vs baseline: 1.0402x; 1.0402x over previous
//
#include <hip/hip_runtime.h>

// Gaussian3D fused single-kernel: values (M,1) + weights (M,N).
// M=8192 points, N=4096 gaussians, F=1.
// d_out layout: [values (M) | weights (M*N)], float32.
//
// One block = 16 point-rows x all 4096 gaussians.
// Each thread owns 16 gaussians: 4 chunks x 4 consecutive n
//   n = c*1024 + t*4 + j   -> float4 weight store is unit-stride across lanes.
// Per-gaussian precompute (quat->R, cov, 3x3 inverse, log2(sigmoid(op)))
// is recomputed per block (cheap VALU, removes a kernel + dependency).
// values[m] finishes in-block: per-thread vs[16] -> batched wave shuffle
// reduce -> 16x4 LDS combine. No atomics (deterministic).

#define THREADS 256
#define JPT 4          // consecutive n per chunk per thread
#define CHUNKS 4       // chunks of N per thread
#define MPB 16         // point rows per block
#define NN 4096
#define MM 8192

__global__ __launch_bounds__(THREADS, 2) void gauss_fused(
    const float* __restrict__ points,
    const float* __restrict__ xyz,
    const float* __restrict__ scale_raw,
    const float* __restrict__ rot_raw,
    const float* __restrict__ op_raw,
    const float* __restrict__ feat,
    float* __restrict__ values,
    float* __restrict__ weights) {
  const int t = threadIdx.x;
  const int mbase = blockIdx.x * MPB;

  // per-thread gaussian params (all statically indexed -> registers)
  float gx[CHUNKS][JPT], gy[CHUNKS][JPT], gz[CHUNKS][JPT];
  float i00[CHUNKS][JPT], i01[CHUNKS][JPT], i02[CHUNKS][JPT];
  float i11[CHUNKS][JPT], i12[CHUNKS][JPT], i22[CHUNKS][JPT];
  float lop[CHUNKS][JPT], gf[CHUNKS][JPT];

#pragma unroll
  for (int c = 0; c < CHUNKS; ++c) {
    const int nb = c * (NN / CHUNKS) + t * JPT;  // multiple of 4
    // vectorized param loads (all 16B-aligned since nb%4==0)
    const float4* rot4 = (const float4*)(rot_raw + 4 * (size_t)nb);
    const float4 q0 = rot4[0], q1 = rot4[1], q2 = rot4[2], q3 = rot4[3];
    const float4* sc4 = (const float4*)(scale_raw + 3 * (size_t)nb);
    const float4 s0 = sc4[0], s1 = sc4[1], s2 = sc4[2];
    const float4* xy4 = (const float4*)(xyz + 3 * (size_t)nb);
    const float4 p0 = xy4[0], p1 = xy4[1], p2 = xy4[2];
    const float4 op4 = *(const float4*)(op_raw + nb);
    const float4 f4  = *(const float4*)(feat + nb);

    const float4 q[JPT] = {q0, q1, q2, q3};
    const float sxa[JPT] = {s0.x, s0.w, s1.z, s2.y};
    const float sya[JPT] = {s0.y, s1.x, s1.w, s2.z};
    const float sza[JPT] = {s0.z, s1.y, s2.x, s2.w};
    const float xxa[JPT] = {p0.x, p0.w, p1.z, p2.y};
    const float yya[JPT] = {p0.y, p1.x, p1.w, p2.z};
    const float zza[JPT] = {p0.z, p1.y, p2.x, p2.w};
    const float opa[JPT] = {op4.x, op4.y, op4.z, op4.w};
    const float fa[JPT]  = {f4.x, f4.y, f4.z, f4.w};

#pragma unroll
    for (int j = 0; j < JPT; ++j) {
      float qw = q[j].x, qx = q[j].y, qy = q[j].z, qz = q[j].w;
      const float inorm = rsqrtf(qw*qw + qx*qx + qy*qy + qz*qz);
      qw *= inorm; qx *= inorm; qy *= inorm; qz *= inorm;
      const float sx = __expf(sxa[j]);
      const float sy = __expf(sya[j]);
      const float sz = __expf(sza[j]);
      const float r00 = 1.f - 2.f*(qy*qy + qz*qz);
      const float r01 = 2.f*(qx*qy - qw*qz);
      const float r02 = 2.f*(qx*qz + qw*qy);
      const float r10 = 2.f*(qx*qy + qw*qz);
      const float r11 = 1.f - 2.f*(qx*qx + qz*qz);
      const float r12 = 2.f*(qy*qz - qw*qx);
      const float r20 = 2.f*(qx*qz - qw*qy);
      const float r21 = 2.f*(qy*qz + qw*qx);
      const float r22 = 1.f - 2.f*(qx*qx + qy*qy);
      // RS[i][k] = R[i][k]*s[k]; cov = RS*RS^T (6 uniques)
      const float a0 = r00*sx, a1 = r01*sy, a2 = r02*sz;
      const float b0 = r10*sx, b1 = r11*sy, b2 = r12*sz;
      const float c0 = r20*sx, c1 = r21*sy, c2 = r22*sz;
      const float c00 = a0*a0 + a1*a1 + a2*a2;
      const float c01 = a0*b0 + a1*b1 + a2*b2;
      const float c02 = a0*c0 + a1*c1 + a2*c2;
      const float c11 = b0*b0 + b1*b1 + b2*b2;
      const float c12 = b0*c0 + b1*c1 + b2*c2;
      const float c22 = c0*c0 + c1*c1 + c2*c2;
      // symmetric 3x3 inverse via adjugate
      const float m00 = c11*c22 - c12*c12;
      const float m01 = c02*c12 - c01*c22;
      const float m02 = c01*c12 - c02*c11;
      const float det = c00*m00 + c01*m01 + c02*m02;
      const float idet = 1.f / det;
      i00[c][j] = m00*idet;
      i01[c][j] = m01*idet;
      i02[c][j] = m02*idet;
      i11[c][j] = (c00*c22 - c02*c02)*idet;
      i12[c][j] = (c02*c01 - c00*c12)*idet;
      i22[c][j] = (c00*c11 - c01*c01)*idet;
      gx[c][j] = xxa[j]; gy[c][j] = yya[j]; gz[c][j] = zza[j];
      // log2(sigmoid(x)) = -log2(1 + exp(-x)); weight folds into exp2 arg
      lop[c][j] = -__log2f(1.f + __expf(-opa[j]));
      gf[c][j] = fa[j];
    }
  }

  float vs[MPB];
  const int wv = t >> 6;
  __shared__ float part[MPB][THREADS / 64];

#pragma unroll 2
  for (int i = 0; i < MPB; ++i) {
    const int m = mbase + i;  // block-uniform -> scalar loads
    const float px = points[3*m+0];
    const float py = points[3*m+1];
    const float pz = points[3*m+2];
    float vsum = 0.f;
#pragma unroll
    for (int c = 0; c < CHUNKS; ++c) {
      float4 w;
#pragma unroll
      for (int j = 0; j < JPT; ++j) {
        const float dx = px - gx[c][j];
        const float dy = py - gy[c][j];
        const float dz = pz - gz[c][j];
        const float t0 = i00[c][j]*dx + i01[c][j]*dy + i02[c][j]*dz;
        const float t1 = i01[c][j]*dx + i11[c][j]*dy + i12[c][j]*dz;
        const float t2 = i02[c][j]*dx + i12[c][j]*dy + i22[c][j]*dz;
        const float mahal = dx*t0 + dy*t1 + dz*t2;
        // exp(-0.5*mahal)*sigmoid(op) = exp2(mahal*(-0.5*log2e) + lop)
        const float wj = exp2f(fmaf(mahal, -0.72134752044448170f, lop[c][j]));
        (&w.x)[j] = wj;
        vsum = fmaf(wj, gf[c][j], vsum);
      }
      *(float4*)&weights[(size_t)m * NN + c * (NN / CHUNKS) + t * JPT] = w;
    }
    vs[i] = vsum;
  }

  // batched wave reduction: 16 independent 6-stage chains (ILP-friendly)
#pragma unroll
  for (int i = 0; i < MPB; ++i) {
#pragma unroll
    for (int off = 32; off >= 1; off >>= 1)
      vs[i] += __shfl_xor(vs[i], off, 64);
  }
  if ((t & 63) == 0) {
#pragma unroll
    for (int i = 0; i < MPB; ++i) part[i][wv] = vs[i];
  }
  __syncthreads();
  if (t < MPB) {
    values[mbase + t] = (part[t][0] + part[t][1]) + (part[t][2] + part[t][3]);
  }
}

extern "C" void kernel_launch(void* const* d_in, const int* in_sizes, int n_in,
                              void* d_out, int out_size, void* d_ws, size_t ws_size,
                              hipStream_t stream) {
  const float* points    = (const float*)d_in[0];
  const float* xyz       = (const float*)d_in[1];
  const float* scale_raw = (const float*)d_in[2];
  const float* rot_raw   = (const float*)d_in[3];
  const float* op_raw    = (const float*)d_in[4];
  const float* feat      = (const float*)d_in[5];

  float* values  = (float*)d_out;        // MM floats
  float* weights = (float*)d_out + MM;   // MM*NN floats

  gauss_fused<<<MM / MPB, THREADS, 0, stream>>>(
      points, xyz, scale_raw, rot_raw, op_raw, feat, values, weights);
}

// Round 4
// 34.461 us; speedup vs baseline: 1.1694x; 1.1242x over previous
//
#include <hip/hip_runtime.h>

// Gaussian3D fused single-kernel: values (M,1) + weights (M,N).
// M=8192 points, N=4096 gaussians, F=1.
// d_out layout: [values (M) | weights (M*N)], float32.
//
// One block = 16 point-rows x all 4096 gaussians; each thread owns 16
// gaussians (4 chunks x 4 consecutive n -> float4 stores unit-stride/lane).
//
// Inner loop uses the EXPANDED quadratic form with all constants folded
// per-gaussian:
//   arg = a00*px^2 + a11*py^2 + a22*pz^2 + a01*px*py + a02*px*pz + a12*py*pz
//       + b0*px + b1*py + b2*pz + c
//   weight = exp2(arg)            (v_exp_f32)
// where a = k*Icov (k=-0.5*log2e, off-diag x2), b = -2k*Icov*g,
//       c = k*g'Icov*g + log2(sigmoid(op)).
// Per pair: 9 FMA + 1 exp2 + 1 FMA (value accum). Point products are 6 muls
// per row, amortized over all 4096 gaussians.

#define THREADS 256
#define JPT 4
#define CHUNKS 4
#define MPB 16
#define NN 4096
#define MM 8192

typedef float f32x4 __attribute__((ext_vector_type(4)));

__global__ __launch_bounds__(THREADS, 2) void gauss_fused(
    const float* __restrict__ points,
    const float* __restrict__ xyz,
    const float* __restrict__ scale_raw,
    const float* __restrict__ rot_raw,
    const float* __restrict__ op_raw,
    const float* __restrict__ feat,
    float* __restrict__ values,
    float* __restrict__ weights) {
  const int t = threadIdx.x;
  const int mbase = blockIdx.x * MPB;

  // per-thread folded gaussian coefficients (statically indexed -> registers)
  float A00[CHUNKS][JPT], A01[CHUNKS][JPT], A02[CHUNKS][JPT];
  float A11[CHUNKS][JPT], A12[CHUNKS][JPT], A22[CHUNKS][JPT];
  float B0[CHUNKS][JPT], B1[CHUNKS][JPT], B2[CHUNKS][JPT];
  float CC[CHUNKS][JPT], FF[CHUNKS][JPT];

  const float k = -0.72134752044448170f;  // -0.5*log2(e)

#pragma unroll
  for (int c = 0; c < CHUNKS; ++c) {
    const int nb = c * (NN / CHUNKS) + t * JPT;  // multiple of 4
    const float4* rot4 = (const float4*)(rot_raw + 4 * (size_t)nb);
    const float4 q0 = rot4[0], q1 = rot4[1], q2 = rot4[2], q3 = rot4[3];
    const float4* sc4 = (const float4*)(scale_raw + 3 * (size_t)nb);
    const float4 s0 = sc4[0], s1 = sc4[1], s2 = sc4[2];
    const float4* xy4 = (const float4*)(xyz + 3 * (size_t)nb);
    const float4 p0 = xy4[0], p1 = xy4[1], p2 = xy4[2];
    const float4 op4 = *(const float4*)(op_raw + nb);
    const float4 f4  = *(const float4*)(feat + nb);

    const float4 q[JPT] = {q0, q1, q2, q3};
    const float sxa[JPT] = {s0.x, s0.w, s1.z, s2.y};
    const float sya[JPT] = {s0.y, s1.x, s1.w, s2.z};
    const float sza[JPT] = {s0.z, s1.y, s2.x, s2.w};
    const float xxa[JPT] = {p0.x, p0.w, p1.z, p2.y};
    const float yya[JPT] = {p0.y, p1.x, p1.w, p2.z};
    const float zza[JPT] = {p0.z, p1.y, p2.x, p2.w};
    const float opa[JPT] = {op4.x, op4.y, op4.z, op4.w};
    const float fa[JPT]  = {f4.x, f4.y, f4.z, f4.w};

#pragma unroll
    for (int j = 0; j < JPT; ++j) {
      float qw = q[j].x, qx = q[j].y, qy = q[j].z, qz = q[j].w;
      const float inorm = rsqrtf(qw*qw + qx*qx + qy*qy + qz*qz);
      qw *= inorm; qx *= inorm; qy *= inorm; qz *= inorm;
      const float sx = __expf(sxa[j]);
      const float sy = __expf(sya[j]);
      const float sz = __expf(sza[j]);
      const float r00 = 1.f - 2.f*(qy*qy + qz*qz);
      const float r01 = 2.f*(qx*qy - qw*qz);
      const float r02 = 2.f*(qx*qz + qw*qy);
      const float r10 = 2.f*(qx*qy + qw*qz);
      const float r11 = 1.f - 2.f*(qx*qx + qz*qz);
      const float r12 = 2.f*(qy*qz - qw*qx);
      const float r20 = 2.f*(qx*qz - qw*qy);
      const float r21 = 2.f*(qy*qz + qw*qx);
      const float r22 = 1.f - 2.f*(qx*qx + qy*qy);
      const float a0 = r00*sx, a1 = r01*sy, a2 = r02*sz;
      const float b0_ = r10*sx, b1_ = r11*sy, b2_ = r12*sz;
      const float c0_ = r20*sx, c1_ = r21*sy, c2_ = r22*sz;
      const float c00 = a0*a0 + a1*a1 + a2*a2;
      const float c01 = a0*b0_ + a1*b1_ + a2*b2_;
      const float c02 = a0*c0_ + a1*c1_ + a2*c2_;
      const float c11 = b0_*b0_ + b1_*b1_ + b2_*b2_;
      const float c12 = b0_*c0_ + b1_*c1_ + b2_*c2_;
      const float c22 = c0_*c0_ + c1_*c1_ + c2_*c2_;
      const float m00 = c11*c22 - c12*c12;
      const float m01 = c02*c12 - c01*c22;
      const float m02 = c01*c12 - c02*c11;
      const float det = c00*m00 + c01*m01 + c02*m02;
      const float idet = 1.f / det;
      const float i00 = m00*idet;
      const float i01 = m01*idet;
      const float i02 = m02*idet;
      const float i11 = (c00*c22 - c02*c02)*idet;
      const float i12 = (c02*c01 - c00*c12)*idet;
      const float i22 = (c00*c11 - c01*c01)*idet;
      const float gx = xxa[j], gy = yya[j], gz = zza[j];
      // I*g
      const float w0 = i00*gx + i01*gy + i02*gz;
      const float w1 = i01*gx + i11*gy + i12*gz;
      const float w2 = i02*gx + i12*gy + i22*gz;
      // folded coefficients
      A00[c][j] = k * i00;
      A11[c][j] = k * i11;
      A22[c][j] = k * i22;
      A01[c][j] = 2.f * k * i01;
      A02[c][j] = 2.f * k * i02;
      A12[c][j] = 2.f * k * i12;
      B0[c][j] = -2.f * k * w0;
      B1[c][j] = -2.f * k * w1;
      B2[c][j] = -2.f * k * w2;
      const float gIg = gx*w0 + gy*w1 + gz*w2;
      const float lop = -__log2f(1.f + __expf(-opa[j]));  // log2(sigmoid)
      CC[c][j] = k * gIg + lop;
      FF[c][j] = fa[j];
    }
  }

  float vs[MPB];
  const int wv = t >> 6;
  __shared__ float part[MPB][THREADS / 64];

#pragma unroll 2
  for (int i = 0; i < MPB; ++i) {
    const int m = mbase + i;  // block-uniform -> scalar loads
    const float px = points[3*m+0];
    const float py = points[3*m+1];
    const float pz = points[3*m+2];
    const float pxx = px*px, pyy = py*py, pzz = pz*pz;
    const float pxy = px*py, pxz = px*pz, pyz = py*pz;
    float vsum = 0.f;
#pragma unroll
    for (int c = 0; c < CHUNKS; ++c) {
      f32x4 w;
#pragma unroll
      for (int j = 0; j < JPT; ++j) {
        float arg = CC[c][j];
        arg = fmaf(B2[c][j], pz, arg);
        arg = fmaf(B1[c][j], py, arg);
        arg = fmaf(B0[c][j], px, arg);
        arg = fmaf(A12[c][j], pyz, arg);
        arg = fmaf(A02[c][j], pxz, arg);
        arg = fmaf(A01[c][j], pxy, arg);
        arg = fmaf(A22[c][j], pzz, arg);
        arg = fmaf(A11[c][j], pyy, arg);
        arg = fmaf(A00[c][j], pxx, arg);
        const float wj = __builtin_amdgcn_exp2f(arg);
        w[j] = wj;
        vsum = fmaf(wj, FF[c][j], vsum);
      }
      __builtin_nontemporal_store(
          w, (f32x4*)&weights[(size_t)m * NN + c * (NN / CHUNKS) + t * JPT]);
    }
    vs[i] = vsum;
  }

  // batched wave reduction: 16 independent 6-stage chains (ILP-friendly)
#pragma unroll
  for (int i = 0; i < MPB; ++i) {
#pragma unroll
    for (int off = 32; off >= 1; off >>= 1)
      vs[i] += __shfl_xor(vs[i], off, 64);
  }
  if ((t & 63) == 0) {
#pragma unroll
    for (int i = 0; i < MPB; ++i) part[i][wv] = vs[i];
  }
  __syncthreads();
  if (t < MPB) {
    values[mbase + t] = (part[t][0] + part[t][1]) + (part[t][2] + part[t][3]);
  }
}

extern "C" void kernel_launch(void* const* d_in, const int* in_sizes, int n_in,
                              void* d_out, int out_size, void* d_ws, size_t ws_size,
                              hipStream_t stream) {
  const float* points    = (const float*)d_in[0];
  const float* xyz       = (const float*)d_in[1];
  const float* scale_raw = (const float*)d_in[2];
  const float* rot_raw   = (const float*)d_in[3];
  const float* op_raw    = (const float*)d_in[4];
  const float* feat      = (const float*)d_in[5];

  float* values  = (float*)d_out;        // MM floats
  float* weights = (float*)d_out + MM;   // MM*NN floats

  gauss_fused<<<MM / MPB, THREADS, 0, stream>>>(
      points, xyz, scale_raw, rot_raw, op_raw, feat, values, weights);
}

// Round 5
// 33.383 us; speedup vs baseline: 1.2071x; 1.0323x over previous
//
#include <hip/hip_runtime.h>

// Gaussian3D, 2-kernel: values (M,1) + weights (M,N). M=8192, N=4096, F=1.
// d_out layout: [values (M) | weights (M*N)], float32.
//
// K1 (precomp): per gaussian, fold everything into 11 coeffs of the expanded
// quadratic  arg(p) = A:pp + B.p + C,  weight = exp2(arg),
// where A = k*Icov (k=-0.5*log2e, off-diag doubled), B = -2k*Icov*g,
// C = k*g'Icov*g + log2(sigmoid(op)); plus FF = feature. Stored SoA
// ws[k*N + n] (180 KB, L2-resident) for coalesced float4 reloads.
//
// K2 (sweep): 1024 blocks x 256 thr, 8 rows/block, chunk-looped so only
// 44 coeff VGPRs are live -> launch_bounds(256,4) = 16 waves/CU for
// store/compute overlap. Plain (L2 write-combined) float4 stores.
// values finish in-block: vs[8] -> batched shuffle reduce -> LDS combine.

#define THREADS 256
#define JPT 4
#define MPB 8
#define NN 4096
#define MM 8192
#define CHUNKS (NN / (THREADS * JPT))  // 4
#define NCOEF 11

typedef float f32x4 __attribute__((ext_vector_type(4)));

// ---------------- kernel 1: fold per-gaussian coefficients ----------------
__global__ void gauss_precomp(const float* __restrict__ xyz,
                              const float* __restrict__ scale_raw,
                              const float* __restrict__ rot_raw,
                              const float* __restrict__ op_raw,
                              const float* __restrict__ feat,
                              float* __restrict__ C, int N) {
  const int n = blockIdx.x * blockDim.x + threadIdx.x;
  if (n >= N) return;
  const float k = -0.72134752044448170f;  // -0.5*log2(e)
  float qw = rot_raw[4*n+0], qx = rot_raw[4*n+1], qy = rot_raw[4*n+2], qz = rot_raw[4*n+3];
  const float inorm = rsqrtf(qw*qw + qx*qx + qy*qy + qz*qz);
  qw *= inorm; qx *= inorm; qy *= inorm; qz *= inorm;
  const float sx = __expf(scale_raw[3*n+0]);
  const float sy = __expf(scale_raw[3*n+1]);
  const float sz = __expf(scale_raw[3*n+2]);
  const float r00 = 1.f - 2.f*(qy*qy + qz*qz);
  const float r01 = 2.f*(qx*qy - qw*qz);
  const float r02 = 2.f*(qx*qz + qw*qy);
  const float r10 = 2.f*(qx*qy + qw*qz);
  const float r11 = 1.f - 2.f*(qx*qx + qz*qz);
  const float r12 = 2.f*(qy*qz - qw*qx);
  const float r20 = 2.f*(qx*qz - qw*qy);
  const float r21 = 2.f*(qy*qz + qw*qx);
  const float r22 = 1.f - 2.f*(qx*qx + qy*qy);
  const float a0 = r00*sx, a1 = r01*sy, a2 = r02*sz;
  const float b0 = r10*sx, b1 = r11*sy, b2 = r12*sz;
  const float c0 = r20*sx, c1 = r21*sy, c2 = r22*sz;
  const float c00 = a0*a0 + a1*a1 + a2*a2;
  const float c01 = a0*b0 + a1*b1 + a2*b2;
  const float c02 = a0*c0 + a1*c1 + a2*c2;
  const float c11 = b0*b0 + b1*b1 + b2*b2;
  const float c12 = b0*c0 + b1*c1 + b2*c2;
  const float c22 = c0*c0 + c1*c1 + c2*c2;
  const float m00 = c11*c22 - c12*c12;
  const float m01 = c02*c12 - c01*c22;
  const float m02 = c01*c12 - c02*c11;
  const float det = c00*m00 + c01*m01 + c02*m02;
  const float idet = 1.f / det;
  const float i00 = m00*idet;
  const float i01 = m01*idet;
  const float i02 = m02*idet;
  const float i11 = (c00*c22 - c02*c02)*idet;
  const float i12 = (c02*c01 - c00*c12)*idet;
  const float i22 = (c00*c11 - c01*c01)*idet;
  const float gx = xyz[3*n+0], gy = xyz[3*n+1], gz = xyz[3*n+2];
  const float w0 = i00*gx + i01*gy + i02*gz;
  const float w1 = i01*gx + i11*gy + i12*gz;
  const float w2 = i02*gx + i12*gy + i22*gz;
  const float gIg = gx*w0 + gy*w1 + gz*w2;
  const float lop = -__log2f(1.f + __expf(-op_raw[n]));  // log2(sigmoid)
  C[0*NN + n] = k * i00;          // A00
  C[1*NN + n] = k * i11;          // A11
  C[2*NN + n] = k * i22;          // A22
  C[3*NN + n] = 2.f * k * i01;    // A01
  C[4*NN + n] = 2.f * k * i02;    // A02
  C[5*NN + n] = 2.f * k * i12;    // A12
  C[6*NN + n] = -2.f * k * w0;    // B0
  C[7*NN + n] = -2.f * k * w1;    // B1
  C[8*NN + n] = -2.f * k * w2;    // B2
  C[9*NN + n] = k * gIg + lop;    // C
  C[10*NN + n] = feat[n];         // FF
}

// ---------------- kernel 2: M x N sweep ----------------
__global__ __launch_bounds__(THREADS, 4) void gauss_sweep(
    const float* __restrict__ points,
    const float* __restrict__ C,
    float* __restrict__ values,
    float* __restrict__ weights) {
  const int t = threadIdx.x;
  const int mbase = blockIdx.x * MPB;

  __shared__ float spts[MPB * 3];
  __shared__ float part[MPB][THREADS / 64];
  if (t < MPB * 3) spts[t] = points[mbase * 3 + t];
  __syncthreads();

  float vs[MPB];
#pragma unroll
  for (int i = 0; i < MPB; ++i) vs[i] = 0.f;

#pragma unroll
  for (int c = 0; c < CHUNKS; ++c) {
    const int n0 = c * (THREADS * JPT) + t * JPT;
    // 11 coalesced float4 coefficient loads (SoA, L2-resident)
    f32x4 A00 = *(const f32x4*)&C[0*NN + n0];
    f32x4 A11 = *(const f32x4*)&C[1*NN + n0];
    f32x4 A22 = *(const f32x4*)&C[2*NN + n0];
    f32x4 A01 = *(const f32x4*)&C[3*NN + n0];
    f32x4 A02 = *(const f32x4*)&C[4*NN + n0];
    f32x4 A12 = *(const f32x4*)&C[5*NN + n0];
    f32x4 B0  = *(const f32x4*)&C[6*NN + n0];
    f32x4 B1  = *(const f32x4*)&C[7*NN + n0];
    f32x4 B2  = *(const f32x4*)&C[8*NN + n0];
    f32x4 CC  = *(const f32x4*)&C[9*NN + n0];
    f32x4 FF  = *(const f32x4*)&C[10*NN + n0];

#pragma unroll
    for (int i = 0; i < MPB; ++i) {
      const float px = spts[3*i+0];
      const float py = spts[3*i+1];
      const float pz = spts[3*i+2];
      const float pxx = px*px, pyy = py*py, pzz = pz*pz;
      const float pxy = px*py, pxz = px*pz, pyz = py*pz;
      f32x4 w;
      float vsum = vs[i];
#pragma unroll
      for (int j = 0; j < JPT; ++j) {
        float arg = CC[j];
        arg = fmaf(B2[j], pz, arg);
        arg = fmaf(B1[j], py, arg);
        arg = fmaf(B0[j], px, arg);
        arg = fmaf(A12[j], pyz, arg);
        arg = fmaf(A02[j], pxz, arg);
        arg = fmaf(A01[j], pxy, arg);
        arg = fmaf(A22[j], pzz, arg);
        arg = fmaf(A11[j], pyy, arg);
        arg = fmaf(A00[j], pxx, arg);
        const float wj = __builtin_amdgcn_exp2f(arg);
        w[j] = wj;
        vsum = fmaf(wj, FF[j], vsum);
      }
      vs[i] = vsum;
      *(f32x4*)&weights[(size_t)(mbase + i) * NN + n0] = w;
    }
  }

  // batched wave reduction: MPB independent 6-stage chains
#pragma unroll
  for (int i = 0; i < MPB; ++i) {
#pragma unroll
    for (int off = 32; off >= 1; off >>= 1)
      vs[i] += __shfl_xor(vs[i], off, 64);
  }
  const int wv = t >> 6;
  if ((t & 63) == 0) {
#pragma unroll
    for (int i = 0; i < MPB; ++i) part[i][wv] = vs[i];
  }
  __syncthreads();
  if (t < MPB) {
    values[mbase + t] = (part[t][0] + part[t][1]) + (part[t][2] + part[t][3]);
  }
}

extern "C" void kernel_launch(void* const* d_in, const int* in_sizes, int n_in,
                              void* d_out, int out_size, void* d_ws, size_t ws_size,
                              hipStream_t stream) {
  const float* points    = (const float*)d_in[0];
  const float* xyz       = (const float*)d_in[1];
  const float* scale_raw = (const float*)d_in[2];
  const float* rot_raw   = (const float*)d_in[3];
  const float* op_raw    = (const float*)d_in[4];
  const float* feat      = (const float*)d_in[5];

  float* values  = (float*)d_out;        // MM floats
  float* weights = (float*)d_out + MM;   // MM*NN floats
  float* C       = (float*)d_ws;         // NCOEF * NN floats = 180 KB

  gauss_precomp<<<(NN + THREADS - 1) / THREADS, THREADS, 0, stream>>>(
      xyz, scale_raw, rot_raw, op_raw, feat, C, NN);

  gauss_sweep<<<MM / MPB, THREADS, 0, stream>>>(points, C, values, weights);
}